// Round 1
// 1036.024 us; speedup vs baseline: 1.0659x; 1.0659x over previous
//
#include <hip/hip_runtime.h>
#include <stdint.h>

// ---------------------------------------------------------------------------
// CustomLSTMCell: B=8192, CIN=512, H=2048
//   xp = x @ Wp^T + bp                        [B,H]
//   comb = tanh(LN_{4096}(concat(xp,h)))      [B,2H]
//   gates g in {f,i,c2,o}: LN_H(comb @ Wg^T + bg) -> sigmoid/tanh
//   cell = LN_H(f*c + i*cc); hid = tanh(LN_H(o*tanh(cell)))
//   out = [hid; cell]  (f32, [2,B,H])
// R3: GEMM rewritten to the 256x256/BK=64 8-phase counted-vmcnt template
//     (T1 XCD swizzle + T2 LDS xor-swizzle + T3/T4 8-phase + T5 setprio).
// ---------------------------------------------------------------------------

typedef __attribute__((ext_vector_type(8))) short short8;
typedef __attribute__((ext_vector_type(4))) float f32x4;

__device__ __forceinline__ unsigned short f2bf(float x) {
  union { float f; uint32_t u; } v; v.f = x;
  uint32_t r = v.u + 0x7FFFu + ((v.u >> 16) & 1u);   // RNE
  return (unsigned short)(r >> 16);
}
__device__ __forceinline__ float bf2f(unsigned short u) {
  union { uint32_t u; float f; } v; v.u = ((uint32_t)u) << 16; return v.f;
}
__device__ __forceinline__ void unpack8(uint4 p, float* o) {
  uint32_t w[4] = {p.x, p.y, p.z, p.w};
#pragma unroll
  for (int k = 0; k < 4; k++) {
    o[2*k]   = bf2f((unsigned short)(w[k] & 0xffffu));
    o[2*k+1] = bf2f((unsigned short)(w[k] >> 16));
  }
}
__device__ __forceinline__ uint4 pack8(const float* s) {
  uint4 r;
  r.x = (uint32_t)f2bf(s[0]) | ((uint32_t)f2bf(s[1]) << 16);
  r.y = (uint32_t)f2bf(s[2]) | ((uint32_t)f2bf(s[3]) << 16);
  r.z = (uint32_t)f2bf(s[4]) | ((uint32_t)f2bf(s[5]) << 16);
  r.w = (uint32_t)f2bf(s[6]) | ((uint32_t)f2bf(s[7]) << 16);
  return r;
}
__device__ __forceinline__ float tanh_fast(float x) {
  x = fminf(fmaxf(x, -15.f), 15.f);
  float e = __expf(-2.f * x);
  return (1.f - e) / (1.f + e);
}
__device__ __forceinline__ float sigmoid_fast(float x) {
  return 1.f / (1.f + __expf(-x));
}

// ---------------------------------------------------------------------------
// Merged f32->bf16 convert for x, W_proj, and the 4 gate weights.
// ---------------------------------------------------------------------------
__global__ __launch_bounds__(256)
void cvt_all(const float* __restrict__ x, const float* __restrict__ Wp,
             const float* __restrict__ Wf, const float* __restrict__ Wi,
             const float* __restrict__ Wc2, const float* __restrict__ Wo,
             unsigned short* __restrict__ xbf, unsigned short* __restrict__ wpbf,
             unsigned short* __restrict__ Wcat) {
  const int blk = blockIdx.x;
  const float* src;
  unsigned short* dst;
  int i;
  if (blk < 2048) {                // x: 524288 groups of 8
    src = x; dst = xbf; i = blk * 256 + threadIdx.x;
  } else if (blk < 2560) {         // W_proj: 131072 groups
    src = Wp; dst = wpbf; i = (blk - 2048) * 256 + threadIdx.x;
  } else {                         // four W's: 1048576 groups each
    int b2 = blk - 2560;
    int w = b2 >> 12;
    src = (w == 0) ? Wf : (w == 1) ? Wi : (w == 2) ? Wc2 : Wo;
    dst = Wcat + (size_t)w * 8388608;
    i = (b2 & 4095) * 256 + threadIdx.x;
  }
  const float4* s4 = (const float4*)src;
  float4 a = s4[2*i], b = s4[2*i+1];
  float t[8] = {a.x,a.y,a.z,a.w,b.x,b.y,b.z,b.w};
  ((uint4*)dst)[i] = pack8(t);
}

// ---------------------------------------------------------------------------
// 8-phase 256x256 GEMM: C[m,n] = sum_k A[m,k]*Bw[n,k] + bias(n), bf16->bf16.
// 512 threads = 8 waves (2M x 4N); per-wave 128x64 out = 8x4 16x16x32 frags.
// BK=64, double-buffered LDS (2 tiles x A,B x 2 halves of 128x64) = 128 KiB.
// LDS rows are 128B; chunk swizzle c ^= (row&7) -> 2-way (free) ds_read_b128.
// global_load_lds writes linearly; swizzle applied on per-lane GLOBAL source.
// Phase = {ds_read subtile; stage 1 half-tile; s_barrier; lgkmcnt(0);
//          setprio(1); 16 MFMA; setprio(0); [vmcnt(2) @ph4/ph8]; s_barrier}.
// Stage/read ledger (iteration i computes tiles t=2i (buf0) and t+1 (buf1)):
//   ph1 A.ks0+B.ks0jh0 reads | stage A1(t+1)   (buf1.A last read prev ph7)
//   ph2 B.ks0jh1             | stage B0(t+1)   (buf1.B last read prev ph8)
//   ph3 A.ks1+B.ks1jh0       | stage B1(t+1)
//   ph4 B.ks1jh1             | stage A0(t+2)   (buf0.A last read ph3) | vmcnt(2)
//   ph5-8: same on buf1      | stage A1(t+2),B0(t+2),B1(t+2),A0(t+3) | vmcnt(2)
// vmcnt(2) @ph4 leaves only A0(t+2) in flight -> t+1 landed before ph5 reads;
// @ph8 leaves only A0(t+3) -> t+2 landed before next ph1. Every stage is
// issued >=1 end-barrier after the last ds_read of the region it overwrites
// (each phase's reads feed that phase's MFMA, so they complete pre-barrier).
// Requires M%256==0, N%256==0, K%128==0, K%8==0 (16B-aligned staging).
// ---------------------------------------------------------------------------
#define MFMA16(a, b, c) __builtin_amdgcn_mfma_f32_16x16x32_bf16((a), (b), (c), 0, 0, 0)
#define GLDS16(g, l)                                                         \
  __builtin_amdgcn_global_load_lds(                                          \
      (const __attribute__((address_space(1))) void*)(g),                    \
      (__attribute__((address_space(3))) void*)(l), 16, 0, 0)

__global__ __launch_bounds__(512, 2)
void gemm_8ph(const unsigned short* __restrict__ A,
              const unsigned short* __restrict__ Bw,
              const float* __restrict__ b0, const float* __restrict__ b1,
              const float* __restrict__ b2, const float* __restrict__ b3,
              unsigned short* __restrict__ C,
              int M, int N, int K) {
  __shared__ __align__(16) unsigned short As[2][2][128][64];
  __shared__ __align__(16) unsigned short Bs[2][2][128][64];

  const int tid  = threadIdx.x;
  const int lane = tid & 63;
  const int wv   = tid >> 6;        // 0..7
  const int wm   = wv >> 2;         // 0..1  (M half)
  const int wn   = wv & 3;          // 0..3  (N quarter)

  // XCD-aware block swizzle (bijective when nwg%8==0; both our shapes are).
  const int nbx = N >> 8;
  const int nwg = (M >> 8) * nbx;
  const int bid = blockIdx.x;
  const int cpx = nwg >> 3;
  const int tile = (nwg & 7) ? bid : (bid & 7) * cpx + (bid >> 3);
  const int bm = (tile / nbx) << 8;
  const int bn = (tile % nbx) << 8;

  // Staging geometry: per load-instr a wave covers 8 rows x 128B; lane l ->
  // row +(l>>3), LDS chunk (l&7). Source chunk pre-swizzled: (l&7)^(row&7).
  const int srow = wv * 8 + (lane >> 3);
  const int schk = (lane & 7) ^ (lane >> 3);
  const unsigned short* ag = A  + (size_t)(bm + srow) * K + schk * 8;
  const unsigned short* bg = Bw + (size_t)(bn + srow) * K + schk * 8;

#define STAGE_A(t, h)                                                        \
  do {                                                                       \
    GLDS16(ag + (size_t)((h) * 128)      * K + (t) * 64,                     \
           &As[(t) & 1][(h)][wv * 8][0]);                                    \
    GLDS16(ag + (size_t)((h) * 128 + 64) * K + (t) * 64,                     \
           &As[(t) & 1][(h)][64 + wv * 8][0]);                               \
  } while (0)
#define STAGE_B(t, h)                                                        \
  do {                                                                       \
    GLDS16(bg + (size_t)((h) * 128)      * K + (t) * 64,                     \
           &Bs[(t) & 1][(h)][wv * 8][0]);                                    \
    GLDS16(bg + (size_t)((h) * 128 + 64) * K + (t) * 64,                     \
           &Bs[(t) & 1][(h)][64 + wv * 8][0]);                               \
  } while (0)

  // Fragment-read geometry: lane cl=row, q=k-chunk; un-swizzle with ^(cl&7).
  const int cl = lane & 15, q = lane >> 4;
  const int ard0 = cl * 64 + ((q       ^ (cl & 7)) * 8);   // ksub 0
  const int ard1 = cl * 64 + (((4 | q) ^ (cl & 7)) * 8);   // ksub 1
  const int brd0 = ((wn & 1) * 64 + cl) * 64 + ((q       ^ (cl & 7)) * 8);
  const int brd1 = ((wn & 1) * 64 + cl) * 64 + (((4 | q) ^ (cl & 7)) * 8);
  const unsigned short* pa0 = &As[0][wm][0][0];
  const unsigned short* pa1 = &As[1][wm][0][0];
  const unsigned short* pb0 = &Bs[0][wn >> 1][0][0];
  const unsigned short* pb1 = &Bs[1][wn >> 1][0][0];

  // Prologue: tile0 fully + A0(tile1); vmcnt(2) leaves A0(tile1) in flight.
  STAGE_A(0, 0); STAGE_A(0, 1); STAGE_B(0, 0); STAGE_B(0, 1);
  STAGE_A(1, 0);

  f32x4 acc[8][4];
#pragma unroll
  for (int r = 0; r < 8; ++r)
#pragma unroll
    for (int j = 0; j < 4; ++j) acc[r][j] = (f32x4){0.f, 0.f, 0.f, 0.f};

  asm volatile("s_waitcnt vmcnt(2)");
  __builtin_amdgcn_s_barrier();

  short8 af[8], bv[4];
  const int NI = K >> 7;              // 2 K-tiles per iteration

  for (int i = 0; i < NI; ++i) {
    const int t = 2 * i;
    const bool pf = (i + 1 < NI);

    // ---- phase 1: buf0 A.ks0 (8) + B.ks0 jh0 (2) | stage A1(t+1) | (ks0,jh0)
#pragma unroll
    for (int r = 0; r < 8; ++r) af[r] = *(const short8*)(pa0 + ard0 + r * 1024);
    bv[0] = *(const short8*)(pb0 + brd0);
    bv[1] = *(const short8*)(pb0 + brd0 + 1024);
    STAGE_A(t + 1, 1);
    __builtin_amdgcn_s_barrier();
    asm volatile("s_waitcnt lgkmcnt(0)");
    __builtin_amdgcn_s_setprio(1);
#pragma unroll
    for (int r = 0; r < 8; ++r) {
      acc[r][0] = MFMA16(af[r], bv[0], acc[r][0]);
      acc[r][1] = MFMA16(af[r], bv[1], acc[r][1]);
    }
    __builtin_amdgcn_s_setprio(0);
    __builtin_amdgcn_s_barrier();

    // ---- phase 2: B.ks0 jh1 (2) | stage B0(t+1) | (ks0,jh1)
    bv[2] = *(const short8*)(pb0 + brd0 + 2048);
    bv[3] = *(const short8*)(pb0 + brd0 + 3072);
    STAGE_B(t + 1, 0);
    __builtin_amdgcn_s_barrier();
    asm volatile("s_waitcnt lgkmcnt(0)");
    __builtin_amdgcn_s_setprio(1);
#pragma unroll
    for (int r = 0; r < 8; ++r) {
      acc[r][2] = MFMA16(af[r], bv[2], acc[r][2]);
      acc[r][3] = MFMA16(af[r], bv[3], acc[r][3]);
    }
    __builtin_amdgcn_s_setprio(0);
    __builtin_amdgcn_s_barrier();

    // ---- phase 3: A.ks1 (8) + B.ks1 jh0 (2) | stage B1(t+1) | (ks1,jh0)
#pragma unroll
    for (int r = 0; r < 8; ++r) af[r] = *(const short8*)(pa0 + ard1 + r * 1024);
    bv[0] = *(const short8*)(pb0 + brd1);
    bv[1] = *(const short8*)(pb0 + brd1 + 1024);
    STAGE_B(t + 1, 1);
    __builtin_amdgcn_s_barrier();
    asm volatile("s_waitcnt lgkmcnt(0)");
    __builtin_amdgcn_s_setprio(1);
#pragma unroll
    for (int r = 0; r < 8; ++r) {
      acc[r][0] = MFMA16(af[r], bv[0], acc[r][0]);
      acc[r][1] = MFMA16(af[r], bv[1], acc[r][1]);
    }
    __builtin_amdgcn_s_setprio(0);
    __builtin_amdgcn_s_barrier();

    // ---- phase 4: B.ks1 jh1 (2) | stage A0(t+2) | (ks1,jh1) | vmcnt
    bv[2] = *(const short8*)(pb0 + brd1 + 2048);
    bv[3] = *(const short8*)(pb0 + brd1 + 3072);
    if (pf) STAGE_A(t + 2, 0);
    __builtin_amdgcn_s_barrier();
    asm volatile("s_waitcnt lgkmcnt(0)");
    __builtin_amdgcn_s_setprio(1);
#pragma unroll
    for (int r = 0; r < 8; ++r) {
      acc[r][2] = MFMA16(af[r], bv[2], acc[r][2]);
      acc[r][3] = MFMA16(af[r], bv[3], acc[r][3]);
    }
    __builtin_amdgcn_s_setprio(0);
    if (pf) { asm volatile("s_waitcnt vmcnt(2)"); }
    else    { asm volatile("s_waitcnt vmcnt(0)"); }
    __builtin_amdgcn_s_barrier();

    // ---- phase 5: buf1 A.ks0 + B.ks0 jh0 | stage A1(t+2) | (ks0,jh0)
#pragma unroll
    for (int r = 0; r < 8; ++r) af[r] = *(const short8*)(pa1 + ard0 + r * 1024);
    bv[0] = *(const short8*)(pb1 + brd0);
    bv[1] = *(const short8*)(pb1 + brd0 + 1024);
    if (pf) STAGE_A(t + 2, 1);
    __builtin_amdgcn_s_barrier();
    asm volatile("s_waitcnt lgkmcnt(0)");
    __builtin_amdgcn_s_setprio(1);
#pragma unroll
    for (int r = 0; r < 8; ++r) {
      acc[r][0] = MFMA16(af[r], bv[0], acc[r][0]);
      acc[r][1] = MFMA16(af[r], bv[1], acc[r][1]);
    }
    __builtin_amdgcn_s_setprio(0);
    __builtin_amdgcn_s_barrier();

    // ---- phase 6: B.ks0 jh1 | stage B0(t+2) | (ks0,jh1)
    bv[2] = *(const short8*)(pb1 + brd0 + 2048);
    bv[3] = *(const short8*)(pb1 + brd0 + 3072);
    if (pf) STAGE_B(t + 2, 0);
    __builtin_amdgcn_s_barrier();
    asm volatile("s_waitcnt lgkmcnt(0)");
    __builtin_amdgcn_s_setprio(1);
#pragma unroll
    for (int r = 0; r < 8; ++r) {
      acc[r][2] = MFMA16(af[r], bv[2], acc[r][2]);
      acc[r][3] = MFMA16(af[r], bv[3], acc[r][3]);
    }
    __builtin_amdgcn_s_setprio(0);
    __builtin_amdgcn_s_barrier();

    // ---- phase 7: A.ks1 + B.ks1 jh0 | stage B1(t+2) | (ks1,jh0)
#pragma unroll
    for (int r = 0; r < 8; ++r) af[r] = *(const short8*)(pa1 + ard1 + r * 1024);
    bv[0] = *(const short8*)(pb1 + brd1);
    bv[1] = *(const short8*)(pb1 + brd1 + 1024);
    if (pf) STAGE_B(t + 2, 1);
    __builtin_amdgcn_s_barrier();
    asm volatile("s_waitcnt lgkmcnt(0)");
    __builtin_amdgcn_s_setprio(1);
#pragma unroll
    for (int r = 0; r < 8; ++r) {
      acc[r][0] = MFMA16(af[r], bv[0], acc[r][0]);
      acc[r][1] = MFMA16(af[r], bv[1], acc[r][1]);
    }
    __builtin_amdgcn_s_setprio(0);
    __builtin_amdgcn_s_barrier();

    // ---- phase 8: B.ks1 jh1 | stage A0(t+3) | (ks1,jh1) | vmcnt
    bv[2] = *(const short8*)(pb1 + brd1 + 2048);
    bv[3] = *(const short8*)(pb1 + brd1 + 3072);
    if (pf) STAGE_A(t + 3, 0);
    __builtin_amdgcn_s_barrier();
    asm volatile("s_waitcnt lgkmcnt(0)");
    __builtin_amdgcn_s_setprio(1);
#pragma unroll
    for (int r = 0; r < 8; ++r) {
      acc[r][2] = MFMA16(af[r], bv[2], acc[r][2]);
      acc[r][3] = MFMA16(af[r], bv[3], acc[r][3]);
    }
    __builtin_amdgcn_s_setprio(0);
    if (pf) { asm volatile("s_waitcnt vmcnt(2)"); }
    __builtin_amdgcn_s_barrier();
  }

  // Epilogue: C/D layout col=lane&15 (n), row=(lane>>4)*4+reg (m).
#pragma unroll
  for (int r8 = 0; r8 < 8; ++r8) {
    const int row0 = bm + wm * 128 + r8 * 16 + q * 4;
#pragma unroll
    for (int j = 0; j < 4; ++j) {
      const int col = bn + wn * 64 + j * 16 + cl;
      const int gate = col >> 11;   // uniform per 16-wide tile
      const float* bp = (gate == 0) ? b0 : (gate == 1) ? b1 : (gate == 2) ? b2 : b3;
      const float bb = bp[col & 2047];
#pragma unroll
      for (int rr = 0; rr < 4; ++rr)
        C[(size_t)(row0 + rr) * N + col] = f2bf(acc[r8][j][rr] + bb);
    }
  }
}
#undef STAGE_A
#undef STAGE_B

__device__ __forceinline__ float2 block_sum2(float a, float b, float* scr, int t) {
#pragma unroll
  for (int o = 32; o; o >>= 1) { a += __shfl_xor(a, o); b += __shfl_xor(b, o); }
  __syncthreads();                       // protect scr from previous use
  if ((t & 63) == 0) { scr[(t >> 6) * 2] = a; scr[(t >> 6) * 2 + 1] = b; }
  __syncthreads();
  return make_float2(scr[0] + scr[2] + scr[4] + scr[6],
                     scr[1] + scr[3] + scr[5] + scr[7]);
}

// LN over concat(xp[b], h[b]) width 4096, then tanh, store bf16 combined row.
__global__ __launch_bounds__(256)
void ln_tanh_combined(const unsigned short* __restrict__ xp,
                      const float* __restrict__ h,
                      const float* __restrict__ g_ln, const float* __restrict__ b_ln,
                      unsigned short* __restrict__ comb) {
  __shared__ float red[8];
  const int b = blockIdx.x, t = threadIdx.x;
  float xv[8], hv[8];
  unpack8(((const uint4*)(xp + (size_t)b * 2048))[t], xv);
  const float4* hr = (const float4*)(h + (size_t)b * 2048);
  float4 h0 = hr[2*t], h1 = hr[2*t+1];
  hv[0]=h0.x; hv[1]=h0.y; hv[2]=h0.z; hv[3]=h0.w;
  hv[4]=h1.x; hv[5]=h1.y; hv[6]=h1.z; hv[7]=h1.w;
  float s = 0.f, ss = 0.f;
#pragma unroll
  for (int e = 0; e < 8; e++) {
    s += xv[e] + hv[e];
    ss += xv[e]*xv[e] + hv[e]*hv[e];
  }
  float2 r = block_sum2(s, ss, red, t);
  float mean = r.x * (1.f/4096.f);
  float var  = r.y * (1.f/4096.f) - mean*mean;
  float rs = rsqrtf(var + 1e-5f);
  float o0[8], o1[8];
  const int j0 = t * 8;
#pragma unroll
  for (int e = 0; e < 8; e++) {
    int j = j0 + e;
    o0[e] = tanh_fast((xv[e] - mean) * rs * g_ln[j] + b_ln[j]);
  }
#pragma unroll
  for (int e = 0; e < 8; e++) {
    int j = 2048 + j0 + e;
    o1[e] = tanh_fast((hv[e] - mean) * rs * g_ln[j] + b_ln[j]);
  }
  uint4* cr = (uint4*)(comb + (size_t)b * 4096);
  cr[t] = pack8(o0);
  cr[256 + t] = pack8(o1);
}

// Per batch row: 4 gate LNs + activations, cell LN, hidden LN, write f32 out.
__global__ __launch_bounds__(256)
void finalize(const unsigned short* __restrict__ gates, const float* __restrict__ c,
              const float* __restrict__ g_f,  const float* __restrict__ bt_f,
              const float* __restrict__ g_i,  const float* __restrict__ bt_i,
              const float* __restrict__ g_c2, const float* __restrict__ bt_c2,
              const float* __restrict__ g_o,  const float* __restrict__ bt_o,
              const float* __restrict__ g_cn, const float* __restrict__ b_cn,
              const float* __restrict__ g_hn, const float* __restrict__ b_hn,
              float* __restrict__ out) {
  __shared__ float red32[32];
  const int b = blockIdx.x, t = threadIdx.x;
  const unsigned short* gr = gates + (size_t)b * 8192;
  float fv[8], iv[8], c2v[8], ov[8];
  unpack8(((const uint4*)(gr        ))[t], fv);
  unpack8(((const uint4*)(gr + 2048))[t], iv);
  unpack8(((const uint4*)(gr + 4096))[t], c2v);
  unpack8(((const uint4*)(gr + 6144))[t], ov);

  float s[8] = {0,0,0,0,0,0,0,0};
#pragma unroll
  for (int e = 0; e < 8; e++) {
    s[0] += fv[e];  s[1] += fv[e]*fv[e];
    s[2] += iv[e];  s[3] += iv[e]*iv[e];
    s[4] += c2v[e]; s[5] += c2v[e]*c2v[e];
    s[6] += ov[e];  s[7] += ov[e]*ov[e];
  }
#pragma unroll
  for (int o = 32; o; o >>= 1)
#pragma unroll
    for (int q2 = 0; q2 < 8; q2++) s[q2] += __shfl_xor(s[q2], o);
  if ((t & 63) == 0) {
#pragma unroll
    for (int q2 = 0; q2 < 8; q2++) red32[(t >> 6) * 8 + q2] = s[q2];
  }
  __syncthreads();
#pragma unroll
  for (int q2 = 0; q2 < 8; q2++)
    s[q2] = red32[q2] + red32[8 + q2] + red32[16 + q2] + red32[24 + q2];

  const float inv = 1.f / 2048.f;
  float m_f = s[0]*inv, rs_f = rsqrtf(s[1]*inv - m_f*m_f + 1e-5f);
  float m_i = s[2]*inv, rs_i = rsqrtf(s[3]*inv - m_i*m_i + 1e-5f);
  float m_c = s[4]*inv, rs_c = rsqrtf(s[5]*inv - m_c*m_c + 1e-5f);
  float m_o = s[6]*inv, rs_o = rsqrtf(s[7]*inv - m_o*m_o + 1e-5f);

  const int j0 = t * 8;
  float cv[8];
  const float4* crp = (const float4*)(c + (size_t)b * 2048);
  float4 c0 = crp[2*t], c1 = crp[2*t+1];
  cv[0]=c0.x; cv[1]=c0.y; cv[2]=c0.z; cv[3]=c0.w;
  cv[4]=c1.x; cv[5]=c1.y; cv[6]=c1.z; cv[7]=c1.w;

  float cellraw[8], os[8];
  float s2 = 0.f, ss2 = 0.f;
#pragma unroll
  for (int e = 0; e < 8; e++) {
    int j = j0 + e;
    float fgate = sigmoid_fast((fv[e]  - m_f) * rs_f * g_f[j]  + bt_f[j]);
    float igate = sigmoid_fast((iv[e]  - m_i) * rs_i * g_i[j]  + bt_i[j]);
    float cgate = tanh_fast   ((c2v[e] - m_c) * rs_c * g_c2[j] + bt_c2[j]);
    os[e]       = sigmoid_fast((ov[e]  - m_o) * rs_o * g_o[j]  + bt_o[j]);
    cellraw[e] = fgate * cv[e] + igate * cgate;
    s2 += cellraw[e]; ss2 += cellraw[e]*cellraw[e];
  }
  float2 rc = block_sum2(s2, ss2, red32, t);
  float m2 = rc.x * inv, rs2 = rsqrtf(rc.y * inv - m2*m2 + 1e-5f);

  float nc[8], hraw[8];
  float s3 = 0.f, ss3 = 0.f;
#pragma unroll
  for (int e = 0; e < 8; e++) {
    int j = j0 + e;
    nc[e] = (cellraw[e] - m2) * rs2 * g_cn[j] + b_cn[j];
    hraw[e] = os[e] * tanh_fast(nc[e]);
    s3 += hraw[e]; ss3 += hraw[e]*hraw[e];
  }
  float2 rh = block_sum2(s3, ss3, red32, t);
  float m3 = rh.x * inv, rs3 = rsqrtf(rh.y * inv - m3*m3 + 1e-5f);

  float nh[8];
#pragma unroll
  for (int e = 0; e < 8; e++) {
    int j = j0 + e;
    nh[e] = tanh_fast((hraw[e] - m3) * rs3 * g_hn[j] + b_hn[j]);
  }
  float4* oh = (float4*)(out + (size_t)b * 2048 + j0);
  oh[0] = make_float4(nh[0], nh[1], nh[2], nh[3]);
  oh[1] = make_float4(nh[4], nh[5], nh[6], nh[7]);
  float4* oc = (float4*)(out + 16777216ull + (size_t)b * 2048 + j0);
  oc[0] = make_float4(nc[0], nc[1], nc[2], nc[3]);
  oc[1] = make_float4(nc[4], nc[5], nc[6], nc[7]);
}

extern "C" void kernel_launch(void* const* d_in, const int* in_sizes, int n_in,
                              void* d_out, int out_size, void* d_ws, size_t ws_size,
                              hipStream_t stream) {
  const float* x      = (const float*)d_in[0];
  const float* h      = (const float*)d_in[1];
  const float* c      = (const float*)d_in[2];
  const float* W_proj = (const float*)d_in[3];
  const float* b_proj = (const float*)d_in[4];
  const float* g_ln   = (const float*)d_in[5];
  const float* b_ln   = (const float*)d_in[6];
  const float* g_cn   = (const float*)d_in[7];
  const float* b_cn   = (const float*)d_in[8];
  const float* g_hn   = (const float*)d_in[9];
  const float* b_hn   = (const float*)d_in[10];
  const float* W_f    = (const float*)d_in[11];
  const float* b_f    = (const float*)d_in[12];
  const float* g_f    = (const float*)d_in[13];
  const float* bt_f   = (const float*)d_in[14];
  const float* W_i    = (const float*)d_in[15];
  const float* b_i    = (const float*)d_in[16];
  const float* g_i    = (const float*)d_in[17];
  const float* bt_i   = (const float*)d_in[18];
  const float* W_c2   = (const float*)d_in[19];
  const float* b_c2   = (const float*)d_in[20];
  const float* g_c2   = (const float*)d_in[21];
  const float* bt_c2  = (const float*)d_in[22];
  const float* W_o    = (const float*)d_in[23];
  const float* b_o    = (const float*)d_in[24];
  const float* g_o    = (const float*)d_in[25];
  const float* bt_o   = (const float*)d_in[26];
  float* out = (float*)d_out;
  char* ws = (char*)d_ws;

  // ws layout (256 MB total):
  //   [0,   64M): Wcat bf16 [8192][4096]  (W_f;W_i;W_c2;W_o)
  //   [64M, 128M): combined bf16 [8192][4096]
  //   [128M,256M): gates bf16 [8192][8192]   (phase 2)
  //     overlaid phase 1: x_bf16 (8M) | wp_bf16 (2M) | xp_bf16 (32M)
  unsigned short* Wcat  = (unsigned short*)(ws);
  unsigned short* comb  = (unsigned short*)(ws + 67108864ull);
  unsigned short* gates = (unsigned short*)(ws + 134217728ull);
  unsigned short* xbf   = (unsigned short*)(ws + 134217728ull);
  unsigned short* wpbf  = (unsigned short*)(ws + 142606336ull);
  unsigned short* xpbf  = (unsigned short*)(ws + 144703488ull);

  // 1) one merged convert launch (x, W_proj, 4 gate weights)
  cvt_all<<<18944, 256, 0, stream>>>(x, W_proj, W_f, W_i, W_c2, W_o,
                                     xbf, wpbf, Wcat);

  // 2) xp = x @ Wp^T + bp   (M=8192, N=2048, K=512) -> bf16; 256 blocks
  gemm_8ph<<<dim3(256), dim3(512), 0, stream>>>(
      xbf, wpbf, b_proj, b_proj, b_proj, b_proj, xpbf, 8192, 2048, 512);

  // 3) combined = tanh(LN(concat(xp,h)))
  ln_tanh_combined<<<8192, 256, 0, stream>>>(xpbf, h, g_ln, b_ln, comb);

  // 4) gates = comb @ Wcat^T + bias   (M=8192, N=8192, K=4096); 1024 blocks
  gemm_8ph<<<dim3(1024), dim3(512), 0, stream>>>(
      comb, Wcat, b_f, b_i, b_c2, b_o, gates, 8192, 8192, 4096);

  // 5) gate LNs + activations + cell/hidden LNs -> out
  finalize<<<8192, 256, 0, stream>>>(gates, c, g_f, bt_f, g_i, bt_i, g_c2, bt_c2,
                                     g_o, bt_o, g_cn, b_cn, g_hn, b_hn, out);
}

// Round 2
// 930.396 us; speedup vs baseline: 1.1870x; 1.1135x over previous
//
#include <hip/hip_runtime.h>
#include <stdint.h>

// ---------------------------------------------------------------------------
// CustomLSTMCell: B=8192, CIN=512, H=2048
//   xp = x @ Wp^T + bp                        [B,H]
//   comb = tanh(LN_{4096}(concat(xp,h)))      [B,2H]
//   gates g in {f,i,c2,o}: LN_H(comb @ Wg^T + bg) -> sigmoid/tanh
//   cell = LN_H(f*c + i*cc); hid = tanh(LN_H(o*tanh(cell)))
//   out = [hid; cell]  (f32, [2,B,H])
// R4: k-split staging units (256 rows x 32 k) so stage units align with what
//     phases read -> issue-to-certify distance 6 phases, 14 loads in flight,
//     vmcnt(10) at even phases (was: 1-3 phase distance, vmcnt(2) drains).
// ---------------------------------------------------------------------------

typedef __attribute__((ext_vector_type(8))) short short8;
typedef __attribute__((ext_vector_type(4))) float f32x4;

__device__ __forceinline__ unsigned short f2bf(float x) {
  union { float f; uint32_t u; } v; v.f = x;
  uint32_t r = v.u + 0x7FFFu + ((v.u >> 16) & 1u);   // RNE
  return (unsigned short)(r >> 16);
}
__device__ __forceinline__ float bf2f(unsigned short u) {
  union { uint32_t u; float f; } v; v.u = ((uint32_t)u) << 16; return v.f;
}
__device__ __forceinline__ void unpack8(uint4 p, float* o) {
  uint32_t w[4] = {p.x, p.y, p.z, p.w};
#pragma unroll
  for (int k = 0; k < 4; k++) {
    o[2*k]   = bf2f((unsigned short)(w[k] & 0xffffu));
    o[2*k+1] = bf2f((unsigned short)(w[k] >> 16));
  }
}
__device__ __forceinline__ uint4 pack8(const float* s) {
  uint4 r;
  r.x = (uint32_t)f2bf(s[0]) | ((uint32_t)f2bf(s[1]) << 16);
  r.y = (uint32_t)f2bf(s[2]) | ((uint32_t)f2bf(s[3]) << 16);
  r.z = (uint32_t)f2bf(s[4]) | ((uint32_t)f2bf(s[5]) << 16);
  r.w = (uint32_t)f2bf(s[6]) | ((uint32_t)f2bf(s[7]) << 16);
  return r;
}
__device__ __forceinline__ float tanh_fast(float x) {
  x = fminf(fmaxf(x, -15.f), 15.f);
  float e = __expf(-2.f * x);
  return (1.f - e) / (1.f + e);
}
__device__ __forceinline__ float sigmoid_fast(float x) {
  return 1.f / (1.f + __expf(-x));
}

// ---------------------------------------------------------------------------
// Merged f32->bf16 convert for x, W_proj, and the 4 gate weights.
// ---------------------------------------------------------------------------
__global__ __launch_bounds__(256)
void cvt_all(const float* __restrict__ x, const float* __restrict__ Wp,
             const float* __restrict__ Wf, const float* __restrict__ Wi,
             const float* __restrict__ Wc2, const float* __restrict__ Wo,
             unsigned short* __restrict__ xbf, unsigned short* __restrict__ wpbf,
             unsigned short* __restrict__ Wcat) {
  const int blk = blockIdx.x;
  const float* src;
  unsigned short* dst;
  int i;
  if (blk < 2048) {                // x: 524288 groups of 8
    src = x; dst = xbf; i = blk * 256 + threadIdx.x;
  } else if (blk < 2560) {         // W_proj: 131072 groups
    src = Wp; dst = wpbf; i = (blk - 2048) * 256 + threadIdx.x;
  } else {                         // four W's: 1048576 groups each
    int b2 = blk - 2560;
    int w = b2 >> 12;
    src = (w == 0) ? Wf : (w == 1) ? Wi : (w == 2) ? Wc2 : Wo;
    dst = Wcat + (size_t)w * 8388608;
    i = (b2 & 4095) * 256 + threadIdx.x;
  }
  const float4* s4 = (const float4*)src;
  float4 a = s4[2*i], b = s4[2*i+1];
  float t[8] = {a.x,a.y,a.z,a.w,b.x,b.y,b.z,b.w};
  ((uint4*)dst)[i] = pack8(t);
}

// ---------------------------------------------------------------------------
// 8-phase 256x256 GEMM, k-split staging. C = A*Bw^T + bias, bf16->bf16.
// 512 threads = 8 waves (2M x 4N); per-wave 128x64 out = 8x4 16x16x32 frags.
// LDS: As/Bs[2 buf][2 ks][256 rows][32 k] bf16 = 128 KiB total.
// Stage unit = one [256][32] block (16 KB, 2 global_load_lds sites/thread).
// Phases read exactly one (matrix, buf, ks) unit:
//   ph1: A(t)ks0 + B(t)ks0 j01   ph2: B(t)ks0 j23
//   ph3: A(t)ks1 + B(t)ks1 j01   ph4: B(t)ks1 j23   ph5-8: same on buf1 (t+1)
// Stage schedule (1 unit/phase; write-window = after region's last read):
//   ph1: B(t+1)ks1 [Bs buf1 ks1 last read prev-ph8]
//   ph2: A(t+2)ks0 [As buf0 ks0 last read ph1]
//   ph3: B(t+2)ks0 [ph2]   ph4: A(t+2)ks1 [ph3]   ph5: B(t+2)ks1 [ph4]
//   ph6: A(t+3)ks0 [ph5]   ph7: B(t+3)ks0 [ph6]   ph8: A(t+3)ks1 [ph7]
// Certify (counted vmcnt before closing barrier; 2 loads/unit):
//   end-ph2: A(t)ks1,B(t)ks1     (7 units in flight -> vmcnt(10))
//   end-ph4: A(t+1)ks0,B(t+1)ks0 (vmcnt(10))
//   end-ph6: A(t+1)ks1,B(t+1)ks1 (vmcnt(10))
//   end-ph8: A(t+2)ks0,B(t+2)ks0 (vmcnt(10))
// Steady state: 14 loads in flight, issue->certify distance = 6 phases.
// Tail (i==NI-1): stages of t+2/t+3 skipped; waits become 8/4/0/none.
// LDS swizzle (64B rows, 4 chunks): slot = q ^ ((row>>1)&3) -> per-8-lane
// subgroup covers all 8 bank-quads. Staging pre-permutes the per-lane GLOBAL
// source chunk ((l&3)^((l>>3)&3)); LDS dest stays linear (glds constraint).
// Requires M%256==0, N%256==0, K%128==0, K>=256.
// ---------------------------------------------------------------------------
#define MFMA16(a, b, c) __builtin_amdgcn_mfma_f32_16x16x32_bf16((a), (b), (c), 0, 0, 0)
#define GLDS16(g, l)                                                         \
  __builtin_amdgcn_global_load_lds(                                          \
      (const __attribute__((address_space(1))) void*)(g),                    \
      (__attribute__((address_space(3))) void*)(l), 16, 0, 0)

__global__ __launch_bounds__(512, 2)
void gemm_8ph(const unsigned short* __restrict__ A,
              const unsigned short* __restrict__ Bw,
              const float* __restrict__ b0, const float* __restrict__ b1,
              const float* __restrict__ b2, const float* __restrict__ b3,
              unsigned short* __restrict__ C,
              int M, int N, int K) {
  __shared__ __align__(16) unsigned short As[2][2][256][32];   // 64 KB
  __shared__ __align__(16) unsigned short Bs[2][2][256][32];   // 64 KB

  const int tid  = threadIdx.x;
  const int lane = tid & 63;
  const int wv   = tid >> 6;        // 0..7
  const int wm   = wv >> 2;         // 0..1  (M half)
  const int wn   = wv & 3;          // 0..3  (N quarter)

  // XCD-aware block swizzle (bijective when nwg%8==0; both our shapes are).
  const int nbx = N >> 8;
  const int nwg = (M >> 8) * nbx;
  const int bid = blockIdx.x;
  const int cpx = nwg >> 3;
  const int tile = (nwg & 7) ? bid : (bid & 7) * cpx + (bid >> 3);
  const int bm = (tile / nbx) << 8;
  const int bn = (tile % nbx) << 8;

  // Staging: per site a wave covers 16 rows x 64B; lane l -> row +(l>>2),
  // LDS slot (l&3). Source chunk pre-swizzled: (l&3) ^ ((l>>3)&3)
  // (= slot ^ f(row), f(row) = (row>>1)&3, row = wv*16 + (l>>2)).
  const int srow = wv * 16 + (lane >> 2);
  const int schk = (lane & 3) ^ ((lane >> 3) & 3);
  const unsigned short* ag = A  + (size_t)(bm + srow) * K + schk * 8;
  const unsigned short* bg = Bw + (size_t)(bn + srow) * K + schk * 8;

#define STAGE_A(t, ks)                                                       \
  do {                                                                       \
    GLDS16(ag + (size_t)(t) * 64 + (ks) * 32,                                \
           &As[(t) & 1][(ks)][wv * 16][0]);                                  \
    GLDS16(ag + (size_t)128 * K + (size_t)(t) * 64 + (ks) * 32,              \
           &As[(t) & 1][(ks)][128 + wv * 16][0]);                            \
  } while (0)
#define STAGE_B(t, ks)                                                       \
  do {                                                                       \
    GLDS16(bg + (size_t)(t) * 64 + (ks) * 32,                                \
           &Bs[(t) & 1][(ks)][wv * 16][0]);                                  \
    GLDS16(bg + (size_t)128 * K + (size_t)(t) * 64 + (ks) * 32,              \
           &Bs[(t) & 1][(ks)][128 + wv * 16][0]);                            \
  } while (0)

  // Fragment reads: row = (wm*128|wn*64) + r*16 + cl, slot = q ^ ((cl>>1)&3)
  // (f(row)=(row>>1)&3 reduces to (cl>>1)&3 since other terms are 0 mod 4).
  const int cl = lane & 15, q = lane >> 4;
  const int fcl = (cl >> 1) & 3;
  const int ard = (wm * 128 + cl) * 32 + ((q ^ fcl) * 8);
  const int brd = (wn * 64 + cl) * 32 + ((q ^ fcl) * 8);
  const unsigned short* pA00 = &As[0][0][0][0] + ard;
  const unsigned short* pA01 = &As[0][1][0][0] + ard;
  const unsigned short* pA10 = &As[1][0][0][0] + ard;
  const unsigned short* pA11 = &As[1][1][0][0] + ard;
  const unsigned short* pB00 = &Bs[0][0][0][0] + brd;
  const unsigned short* pB01 = &Bs[0][1][0][0] + brd;
  const unsigned short* pB10 = &Bs[1][0][0][0] + brd;
  const unsigned short* pB11 = &Bs[1][1][0][0] + brd;

  // Prologue: 7 units (14 loads); certify A(0)ks0,B(0)ks0 -> vmcnt(10).
  STAGE_A(0, 0); STAGE_B(0, 0); STAGE_A(0, 1); STAGE_B(0, 1);
  STAGE_A(1, 0); STAGE_B(1, 0); STAGE_A(1, 1);

  f32x4 acc[8][4];
#pragma unroll
  for (int r = 0; r < 8; ++r)
#pragma unroll
    for (int j = 0; j < 4; ++j) acc[r][j] = (f32x4){0.f, 0.f, 0.f, 0.f};

  asm volatile("s_waitcnt vmcnt(10)");
  __builtin_amdgcn_s_barrier();

  short8 af[8], bv[4];
  const int NI = K >> 7;              // 2 K-tiles (of 64) per iteration

  for (int i = 0; i < NI; ++i) {
    const int t = 2 * i;
    const bool pf = (i + 1 < NI);

    // ---- ph1: read A(buf0,ks0)+B(buf0,ks0)j01 | stage B(t+1)ks1
#pragma unroll
    for (int r = 0; r < 8; ++r) af[r] = *(const short8*)(pA00 + r * 512);
    bv[0] = *(const short8*)(pB00);
    bv[1] = *(const short8*)(pB00 + 512);
    STAGE_B(t + 1, 1);
    __builtin_amdgcn_s_barrier();
    asm volatile("s_waitcnt lgkmcnt(0)");
    __builtin_amdgcn_s_setprio(1);
#pragma unroll
    for (int r = 0; r < 8; ++r) {
      acc[r][0] = MFMA16(af[r], bv[0], acc[r][0]);
      acc[r][1] = MFMA16(af[r], bv[1], acc[r][1]);
    }
    __builtin_amdgcn_s_setprio(0);
    __builtin_amdgcn_s_barrier();

    // ---- ph2: read B(buf0,ks0)j23 | stage A(t+2)ks0 | certify (t)ks1
    bv[2] = *(const short8*)(pB00 + 1024);
    bv[3] = *(const short8*)(pB00 + 1536);
    if (pf) STAGE_A(t + 2, 0);
    __builtin_amdgcn_s_barrier();
    asm volatile("s_waitcnt lgkmcnt(0)");
    __builtin_amdgcn_s_setprio(1);
#pragma unroll
    for (int r = 0; r < 8; ++r) {
      acc[r][2] = MFMA16(af[r], bv[2], acc[r][2]);
      acc[r][3] = MFMA16(af[r], bv[3], acc[r][3]);
    }
    __builtin_amdgcn_s_setprio(0);
    if (pf) { asm volatile("s_waitcnt vmcnt(10)"); }
    else    { asm volatile("s_waitcnt vmcnt(8)");  }
    __builtin_amdgcn_s_barrier();

    // ---- ph3: read A(buf0,ks1)+B(buf0,ks1)j01 | stage B(t+2)ks0
#pragma unroll
    for (int r = 0; r < 8; ++r) af[r] = *(const short8*)(pA01 + r * 512);
    bv[0] = *(const short8*)(pB01);
    bv[1] = *(const short8*)(pB01 + 512);
    if (pf) STAGE_B(t + 2, 0);
    __builtin_amdgcn_s_barrier();
    asm volatile("s_waitcnt lgkmcnt(0)");
    __builtin_amdgcn_s_setprio(1);
#pragma unroll
    for (int r = 0; r < 8; ++r) {
      acc[r][0] = MFMA16(af[r], bv[0], acc[r][0]);
      acc[r][1] = MFMA16(af[r], bv[1], acc[r][1]);
    }
    __builtin_amdgcn_s_setprio(0);
    __builtin_amdgcn_s_barrier();

    // ---- ph4: read B(buf0,ks1)j23 | stage A(t+2)ks1 | certify (t+1)ks0
    bv[2] = *(const short8*)(pB01 + 1024);
    bv[3] = *(const short8*)(pB01 + 1536);
    if (pf) STAGE_A(t + 2, 1);
    __builtin_amdgcn_s_barrier();
    asm volatile("s_waitcnt lgkmcnt(0)");
    __builtin_amdgcn_s_setprio(1);
#pragma unroll
    for (int r = 0; r < 8; ++r) {
      acc[r][2] = MFMA16(af[r], bv[2], acc[r][2]);
      acc[r][3] = MFMA16(af[r], bv[3], acc[r][3]);
    }
    __builtin_amdgcn_s_setprio(0);
    if (pf) { asm volatile("s_waitcnt vmcnt(10)"); }
    else    { asm volatile("s_waitcnt vmcnt(4)");  }
    __builtin_amdgcn_s_barrier();

    // ---- ph5: read A(buf1,ks0)+B(buf1,ks0)j01 | stage B(t+2)ks1
#pragma unroll
    for (int r = 0; r < 8; ++r) af[r] = *(const short8*)(pA10 + r * 512);
    bv[0] = *(const short8*)(pB10);
    bv[1] = *(const short8*)(pB10 + 512);
    if (pf) STAGE_B(t + 2, 1);
    __builtin_amdgcn_s_barrier();
    asm volatile("s_waitcnt lgkmcnt(0)");
    __builtin_amdgcn_s_setprio(1);
#pragma unroll
    for (int r = 0; r < 8; ++r) {
      acc[r][0] = MFMA16(af[r], bv[0], acc[r][0]);
      acc[r][1] = MFMA16(af[r], bv[1], acc[r][1]);
    }
    __builtin_amdgcn_s_setprio(0);
    __builtin_amdgcn_s_barrier();

    // ---- ph6: read B(buf1,ks0)j23 | stage A(t+3)ks0 | certify (t+1)ks1
    bv[2] = *(const short8*)(pB10 + 1024);
    bv[3] = *(const short8*)(pB10 + 1536);
    if (pf) STAGE_A(t + 3, 0);
    __builtin_amdgcn_s_barrier();
    asm volatile("s_waitcnt lgkmcnt(0)");
    __builtin_amdgcn_s_setprio(1);
#pragma unroll
    for (int r = 0; r < 8; ++r) {
      acc[r][2] = MFMA16(af[r], bv[2], acc[r][2]);
      acc[r][3] = MFMA16(af[r], bv[3], acc[r][3]);
    }
    __builtin_amdgcn_s_setprio(0);
    if (pf) { asm volatile("s_waitcnt vmcnt(10)"); }
    else    { asm volatile("s_waitcnt vmcnt(0)");  }
    __builtin_amdgcn_s_barrier();

    // ---- ph7: read A(buf1,ks1)+B(buf1,ks1)j01 | stage B(t+3)ks0
#pragma unroll
    for (int r = 0; r < 8; ++r) af[r] = *(const short8*)(pA11 + r * 512);
    bv[0] = *(const short8*)(pB11);
    bv[1] = *(const short8*)(pB11 + 512);
    if (pf) STAGE_B(t + 3, 0);
    __builtin_amdgcn_s_barrier();
    asm volatile("s_waitcnt lgkmcnt(0)");
    __builtin_amdgcn_s_setprio(1);
#pragma unroll
    for (int r = 0; r < 8; ++r) {
      acc[r][0] = MFMA16(af[r], bv[0], acc[r][0]);
      acc[r][1] = MFMA16(af[r], bv[1], acc[r][1]);
    }
    __builtin_amdgcn_s_setprio(0);
    __builtin_amdgcn_s_barrier();

    // ---- ph8: read B(buf1,ks1)j23 | stage A(t+3)ks1 | certify (t+2)ks0
    bv[2] = *(const short8*)(pB11 + 1024);
    bv[3] = *(const short8*)(pB11 + 1536);
    if (pf) STAGE_A(t + 3, 1);
    __builtin_amdgcn_s_barrier();
    asm volatile("s_waitcnt lgkmcnt(0)");
    __builtin_amdgcn_s_setprio(1);
#pragma unroll
    for (int r = 0; r < 8; ++r) {
      acc[r][2] = MFMA16(af[r], bv[2], acc[r][2]);
      acc[r][3] = MFMA16(af[r], bv[3], acc[r][3]);
    }
    __builtin_amdgcn_s_setprio(0);
    if (pf) { asm volatile("s_waitcnt vmcnt(10)"); }
    __builtin_amdgcn_s_barrier();
  }

  // Epilogue: C/D layout col=lane&15 (n), row=(lane>>4)*4+reg (m).
#pragma unroll
  for (int r8 = 0; r8 < 8; ++r8) {
    const int row0 = bm + wm * 128 + r8 * 16 + q * 4;
#pragma unroll
    for (int j = 0; j < 4; ++j) {
      const int col = bn + wn * 64 + j * 16 + cl;
      const int gate = col >> 11;   // uniform per 16-wide tile
      const float* bp = (gate == 0) ? b0 : (gate == 1) ? b1 : (gate == 2) ? b2 : b3;
      const float bb = bp[col & 2047];
#pragma unroll
      for (int rr = 0; rr < 4; ++rr)
        C[(size_t)(row0 + rr) * N + col] = f2bf(acc[r8][j][rr] + bb);
    }
  }
}
#undef STAGE_A
#undef STAGE_B

__device__ __forceinline__ float2 block_sum2(float a, float b, float* scr, int t) {
#pragma unroll
  for (int o = 32; o; o >>= 1) { a += __shfl_xor(a, o); b += __shfl_xor(b, o); }
  __syncthreads();                       // protect scr from previous use
  if ((t & 63) == 0) { scr[(t >> 6) * 2] = a; scr[(t >> 6) * 2 + 1] = b; }
  __syncthreads();
  return make_float2(scr[0] + scr[2] + scr[4] + scr[6],
                     scr[1] + scr[3] + scr[5] + scr[7]);
}

// LN over concat(xp[b], h[b]) width 4096, then tanh, store bf16 combined row.
__global__ __launch_bounds__(256)
void ln_tanh_combined(const unsigned short* __restrict__ xp,
                      const float* __restrict__ h,
                      const float* __restrict__ g_ln, const float* __restrict__ b_ln,
                      unsigned short* __restrict__ comb) {
  __shared__ float red[8];
  const int b = blockIdx.x, t = threadIdx.x;
  float xv[8], hv[8];
  unpack8(((const uint4*)(xp + (size_t)b * 2048))[t], xv);
  const float4* hr = (const float4*)(h + (size_t)b * 2048);
  float4 h0 = hr[2*t], h1 = hr[2*t+1];
  hv[0]=h0.x; hv[1]=h0.y; hv[2]=h0.z; hv[3]=h0.w;
  hv[4]=h1.x; hv[5]=h1.y; hv[6]=h1.z; hv[7]=h1.w;
  float s = 0.f, ss = 0.f;
#pragma unroll
  for (int e = 0; e < 8; e++) {
    s += xv[e] + hv[e];
    ss += xv[e]*xv[e] + hv[e]*hv[e];
  }
  float2 r = block_sum2(s, ss, red, t);
  float mean = r.x * (1.f/4096.f);
  float var  = r.y * (1.f/4096.f) - mean*mean;
  float rs = rsqrtf(var + 1e-5f);
  float o0[8], o1[8];
  const int j0 = t * 8;
#pragma unroll
  for (int e = 0; e < 8; e++) {
    int j = j0 + e;
    o0[e] = tanh_fast((xv[e] - mean) * rs * g_ln[j] + b_ln[j]);
  }
#pragma unroll
  for (int e = 0; e < 8; e++) {
    int j = 2048 + j0 + e;
    o1[e] = tanh_fast((hv[e] - mean) * rs * g_ln[j] + b_ln[j]);
  }
  uint4* cr = (uint4*)(comb + (size_t)b * 4096);
  cr[t] = pack8(o0);
  cr[256 + t] = pack8(o1);
}

// Per batch row: 4 gate LNs + activations, cell LN, hidden LN, write f32 out.
__global__ __launch_bounds__(256)
void finalize(const unsigned short* __restrict__ gates, const float* __restrict__ c,
              const float* __restrict__ g_f,  const float* __restrict__ bt_f,
              const float* __restrict__ g_i,  const float* __restrict__ bt_i,
              const float* __restrict__ g_c2, const float* __restrict__ bt_c2,
              const float* __restrict__ g_o,  const float* __restrict__ bt_o,
              const float* __restrict__ g_cn, const float* __restrict__ b_cn,
              const float* __restrict__ g_hn, const float* __restrict__ b_hn,
              float* __restrict__ out) {
  __shared__ float red32[32];
  const int b = blockIdx.x, t = threadIdx.x;
  const unsigned short* gr = gates + (size_t)b * 8192;
  float fv[8], iv[8], c2v[8], ov[8];
  unpack8(((const uint4*)(gr        ))[t], fv);
  unpack8(((const uint4*)(gr + 2048))[t], iv);
  unpack8(((const uint4*)(gr + 4096))[t], c2v);
  unpack8(((const uint4*)(gr + 6144))[t], ov);

  float s[8] = {0,0,0,0,0,0,0,0};
#pragma unroll
  for (int e = 0; e < 8; e++) {
    s[0] += fv[e];  s[1] += fv[e]*fv[e];
    s[2] += iv[e];  s[3] += iv[e]*iv[e];
    s[4] += c2v[e]; s[5] += c2v[e]*c2v[e];
    s[6] += ov[e];  s[7] += ov[e]*ov[e];
  }
#pragma unroll
  for (int o = 32; o; o >>= 1)
#pragma unroll
    for (int q2 = 0; q2 < 8; q2++) s[q2] += __shfl_xor(s[q2], o);
  if ((t & 63) == 0) {
#pragma unroll
    for (int q2 = 0; q2 < 8; q2++) red32[(t >> 6) * 8 + q2] = s[q2];
  }
  __syncthreads();
#pragma unroll
  for (int q2 = 0; q2 < 8; q2++)
    s[q2] = red32[q2] + red32[8 + q2] + red32[16 + q2] + red32[24 + q2];

  const float inv = 1.f / 2048.f;
  float m_f = s[0]*inv, rs_f = rsqrtf(s[1]*inv - m_f*m_f + 1e-5f);
  float m_i = s[2]*inv, rs_i = rsqrtf(s[3]*inv - m_i*m_i + 1e-5f);
  float m_c = s[4]*inv, rs_c = rsqrtf(s[5]*inv - m_c*m_c + 1e-5f);
  float m_o = s[6]*inv, rs_o = rsqrtf(s[7]*inv - m_o*m_o + 1e-5f);

  const int j0 = t * 8;
  float cv[8];
  const float4* crp = (const float4*)(c + (size_t)b * 2048);
  float4 c0 = crp[2*t], c1 = crp[2*t+1];
  cv[0]=c0.x; cv[1]=c0.y; cv[2]=c0.z; cv[3]=c0.w;
  cv[4]=c1.x; cv[5]=c1.y; cv[6]=c1.z; cv[7]=c1.w;

  float cellraw[8], os[8];
  float s2 = 0.f, ss2 = 0.f;
#pragma unroll
  for (int e = 0; e < 8; e++) {
    int j = j0 + e;
    float fgate = sigmoid_fast((fv[e]  - m_f) * rs_f * g_f[j]  + bt_f[j]);
    float igate = sigmoid_fast((iv[e]  - m_i) * rs_i * g_i[j]  + bt_i[j]);
    float cgate = tanh_fast   ((c2v[e] - m_c) * rs_c * g_c2[j] + bt_c2[j]);
    os[e]       = sigmoid_fast((ov[e]  - m_o) * rs_o * g_o[j]  + bt_o[j]);
    cellraw[e] = fgate * cv[e] + igate * cgate;
    s2 += cellraw[e]; ss2 += cellraw[e]*cellraw[e];
  }
  float2 rc = block_sum2(s2, ss2, red32, t);
  float m2 = rc.x * inv, rs2 = rsqrtf(rc.y * inv - m2*m2 + 1e-5f);

  float nc[8], hraw[8];
  float s3 = 0.f, ss3 = 0.f;
#pragma unroll
  for (int e = 0; e < 8; e++) {
    int j = j0 + e;
    nc[e] = (cellraw[e] - m2) * rs2 * g_cn[j] + b_cn[j];
    hraw[e] = os[e] * tanh_fast(nc[e]);
    s3 += hraw[e]; ss3 += hraw[e]*hraw[e];
  }
  float2 rh = block_sum2(s3, ss3, red32, t);
  float m3 = rh.x * inv, rs3 = rsqrtf(rh.y * inv - m3*m3 + 1e-5f);

  float nh[8];
#pragma unroll
  for (int e = 0; e < 8; e++) {
    int j = j0 + e;
    nh[e] = tanh_fast((hraw[e] - m3) * rs3 * g_hn[j] + b_hn[j]);
  }
  float4* oh = (float4*)(out + (size_t)b * 2048 + j0);
  oh[0] = make_float4(nh[0], nh[1], nh[2], nh[3]);
  oh[1] = make_float4(nh[4], nh[5], nh[6], nh[7]);
  float4* oc = (float4*)(out + 16777216ull + (size_t)b * 2048 + j0);
  oc[0] = make_float4(nc[0], nc[1], nc[2], nc[3]);
  oc[1] = make_float4(nc[4], nc[5], nc[6], nc[7]);
}

extern "C" void kernel_launch(void* const* d_in, const int* in_sizes, int n_in,
                              void* d_out, int out_size, void* d_ws, size_t ws_size,
                              hipStream_t stream) {
  const float* x      = (const float*)d_in[0];
  const float* h      = (const float*)d_in[1];
  const float* c      = (const float*)d_in[2];
  const float* W_proj = (const float*)d_in[3];
  const float* b_proj = (const float*)d_in[4];
  const float* g_ln   = (const float*)d_in[5];
  const float* b_ln   = (const float*)d_in[6];
  const float* g_cn   = (const float*)d_in[7];
  const float* b_cn   = (const float*)d_in[8];
  const float* g_hn   = (const float*)d_in[9];
  const float* b_hn   = (const float*)d_in[10];
  const float* W_f    = (const float*)d_in[11];
  const float* b_f    = (const float*)d_in[12];
  const float* g_f    = (const float*)d_in[13];
  const float* bt_f   = (const float*)d_in[14];
  const float* W_i    = (const float*)d_in[15];
  const float* b_i    = (const float*)d_in[16];
  const float* g_i    = (const float*)d_in[17];
  const float* bt_i   = (const float*)d_in[18];
  const float* W_c2   = (const float*)d_in[19];
  const float* b_c2   = (const float*)d_in[20];
  const float* g_c2   = (const float*)d_in[21];
  const float* bt_c2  = (const float*)d_in[22];
  const float* W_o    = (const float*)d_in[23];
  const float* b_o    = (const float*)d_in[24];
  const float* g_o    = (const float*)d_in[25];
  const float* bt_o   = (const float*)d_in[26];
  float* out = (float*)d_out;
  char* ws = (char*)d_ws;

  // ws layout (256 MB total):
  //   [0,   64M): Wcat bf16 [8192][4096]  (W_f;W_i;W_c2;W_o)
  //   [64M, 128M): combined bf16 [8192][4096]
  //   [128M,256M): gates bf16 [8192][8192]   (phase 2)
  //     overlaid phase 1: x_bf16 (8M) | wp_bf16 (2M) | xp_bf16 (32M)
  unsigned short* Wcat  = (unsigned short*)(ws);
  unsigned short* comb  = (unsigned short*)(ws + 67108864ull);
  unsigned short* gates = (unsigned short*)(ws + 134217728ull);
  unsigned short* xbf   = (unsigned short*)(ws + 134217728ull);
  unsigned short* wpbf  = (unsigned short*)(ws + 142606336ull);
  unsigned short* xpbf  = (unsigned short*)(ws + 144703488ull);

  // 1) one merged convert launch (x, W_proj, 4 gate weights)
  cvt_all<<<18944, 256, 0, stream>>>(x, W_proj, W_f, W_i, W_c2, W_o,
                                     xbf, wpbf, Wcat);

  // 2) xp = x @ Wp^T + bp   (M=8192, N=2048, K=512) -> bf16; 256 blocks
  gemm_8ph<<<dim3(256), dim3(512), 0, stream>>>(
      xbf, wpbf, b_proj, b_proj, b_proj, b_proj, xpbf, 8192, 2048, 512);

  // 3) combined = tanh(LN(concat(xp,h)))
  ln_tanh_combined<<<8192, 256, 0, stream>>>(xpbf, h, g_ln, b_ln, comb);

  // 4) gates = comb @ Wcat^T + bias   (M=8192, N=8192, K=4096); 1024 blocks
  gemm_8ph<<<dim3(1024), dim3(512), 0, stream>>>(
      comb, Wcat, b_f, b_i, b_c2, b_o, gates, 8192, 8192, 4096);

  // 5) gate LNs + activations + cell/hidden LNs -> out
  finalize<<<8192, 256, 0, stream>>>(gates, c, g_f, bt_f, g_i, bt_i, g_c2, bt_c2,
                                     g_o, bt_o, g_cn, b_cn, g_hn, b_hn, out);
}